// Round 2
// baseline (1307.410 us; speedup 1.0000x reference)
//
#include <hip/hip_runtime.h>

// CapsuleLayer routing, algebraically collapsed:
//   u_hat[b,j,i,d] = sum_p W[j,i,d,p] * x[b,i,p]
//   s0[b,j,d]      = sum_i u_hat[b,j,i,d]
//   G[b,j,d,e]     = sum_i u_hat[b,j,i,d]*u_hat[b,j,i,e]   (16x16 Gram, symmetric)
//   out_r = s_r / ||s_r||^2 ;  s_{r+1} = s_r + G*out_r ;  return out_2
// One kernel: per-(b,j) Gram accumulation + fused routing tail.
// Exactness: c only enters through U^T c; c_{r+1} = c_r + U*out_r implies
// s_{r+1} = s_r + (U^T U)*out_r — no u_hat materialization needed.

#define BB 64
#define JJ 64
#define II 4096
#define DD 16
#define PP 8
#define NTRI 136   // 16*17/2
#define BT 8       // b's per block (one per wave)

__global__ __launch_bounds__(512, 2) void caps_kernel(
    const float* __restrict__ x,   // [B, I, P]
    const float* __restrict__ W,   // [J, I, D, P]
    float* __restrict__ out)       // [B, J, D]
{
    const int bid  = blockIdx.x;          // bid = bg*64 + j  -> same-j blocks share XCD L2
    const int j    = bid & 63;
    const int bg   = bid >> 6;
    const int wave = threadIdx.x >> 6;
    const int lane = threadIdx.x & 63;
    const int b    = bg * BT + wave;

    const float* xb = x + (size_t)b * (II * PP);
    const float* Wj = W + (size_t)j * ((size_t)II * DD * PP);

    float tri[NTRI];
    float s0[DD];
#pragma unroll
    for (int k = 0; k < NTRI; ++k) tri[k] = 0.0f;
#pragma unroll
    for (int d = 0; d < DD; ++d) s0[d] = 0.0f;

    for (int t = 0; t < II / 64; ++t) {
        const int i = t * 64 + lane;
        const float4* wp = (const float4*)(Wj + (size_t)i * (DD * PP));
        const float4* xp = (const float4*)(xb + (size_t)i * PP);
        const float4 x0 = xp[0];
        const float4 x1 = xp[1];

        float v[DD];
#pragma unroll
        for (int d = 0; d < DD; ++d) {
            const float4 w0 = wp[2 * d];
            const float4 w1 = wp[2 * d + 1];
            v[d] = w0.x * x0.x + w0.y * x0.y + w0.z * x0.z + w0.w * x0.w
                 + w1.x * x1.x + w1.y * x1.y + w1.z * x1.z + w1.w * x1.w;
        }

        int k = 0;
#pragma unroll
        for (int d = 0; d < DD; ++d) {
            s0[d] += v[d];
#pragma unroll
            for (int e = d; e < DD; ++e) {
                tri[k] += v[d] * v[e];
                ++k;
            }
        }
    }

    // Wave-level tree reduction (each wave owns a distinct b -> independent).
#pragma unroll
    for (int off = 32; off > 0; off >>= 1) {
#pragma unroll
        for (int d = 0; d < DD; ++d) s0[d] += __shfl_down(s0[d], off);
#pragma unroll
        for (int k = 0; k < NTRI; ++k) tri[k] += __shfl_down(tri[k], off);
    }

    // Routing tail on lane 0 (152 scalars; 3 fixed-point steps).
    if (lane == 0) {
        float s[DD], u[DD];
#pragma unroll
        for (int d = 0; d < DD; ++d) s[d] = s0[d];

        for (int r = 0; r < 3; ++r) {
            float n = 0.0f;
#pragma unroll
            for (int d = 0; d < DD; ++d) n += s[d] * s[d];
            const float inv = 1.0f / n;   // reference divides by squared norm
#pragma unroll
            for (int d = 0; d < DD; ++d) u[d] = s[d] * inv;

            if (r < 2) {
                float nv[DD];
#pragma unroll
                for (int d = 0; d < DD; ++d) nv[d] = 0.0f;
                int k = 0;
#pragma unroll
                for (int d = 0; d < DD; ++d) {
#pragma unroll
                    for (int e = d; e < DD; ++e) {
                        const float w = tri[k];
                        ++k;
                        nv[d] += w * u[e];
                        if (e > d) nv[e] += w * u[d];
                    }
                }
#pragma unroll
                for (int d = 0; d < DD; ++d) s[d] += nv[d];
            }
        }

        float* op = out + ((size_t)b * JJ + j) * DD;
#pragma unroll
        for (int d = 0; d < DD; ++d) op[d] = u[d];
    }
}

extern "C" void kernel_launch(void* const* d_in, const int* in_sizes, int n_in,
                              void* d_out, int out_size, void* d_ws, size_t ws_size,
                              hipStream_t stream) {
    const float* x = (const float*)d_in[0];   // inputs [64, 4096, 8]
    const float* W = (const float*)d_in[1];   // W      [64, 4096, 16, 8]
    float* out = (float*)d_out;               // [64, 64, 16]

    dim3 grid((BB / BT) * JJ);                // 8 b-groups * 64 j = 512 blocks
    dim3 block(512);
    caps_kernel<<<grid, block, 0, stream>>>(x, W, out);
}

// Round 3
// 676.196 us; speedup vs baseline: 1.9335x; 1.9335x over previous
//
#include <hip/hip_runtime.h>
#include <hip/hip_bf16.h>

// CapsuleLayer routing, algebraically collapsed (exact):
//   v[b,j,i,d] = sum_p W[j,i,d,p] * x[b,i,p]       (u_hat)
//   s0[d] = sum_i v[i,d];  G[d,e] = sum_i v[i,d]*v[i,e]   per (b,j)
//   u = s/||s||^2 ; s <- s + G*u  (x2) ; return u
// Gram computed on the matrix pipe: G = U^T U via mfma_f32_16x16x32_bf16
// with IDENTICAL A/B fragments (lane l holds v[i][d], d=l&15,
// i=base+(l>>4)*8+jj, jj=0..7). Gram is k-permutation-invariant, so
// within-chunk k ordering cannot cause a correctness bug.
// Persistent per-lane state: 4 (acc) + 1 (s0) regs -> no spills
// (round-2 kernel spilled tri[136] -> 542 MB scratch writes).

#define BB 64
#define JJ 64
#define II 4096
#define DD 16
#define PP 8

typedef __attribute__((ext_vector_type(8))) short bf16x8;
typedef __attribute__((ext_vector_type(4))) float f32x4;

__global__ __launch_bounds__(512, 4) void caps_kernel(
    const float* __restrict__ x,   // [B, I, P]
    const float* __restrict__ W,   // [J, I, D, P]
    float* __restrict__ out)       // [B, J, D]
{
    const int bid  = blockIdx.x;      // bid = bg*64 + j -> same-j blocks land on same XCD (bid%8 = j%8)
    const int j    = bid & 63;
    const int bg   = bid >> 6;
    const int wave = threadIdx.x >> 6;
    const int lane = threadIdx.x & 63;
    const int b    = bg * 8 + wave;   // one b per wave, one j per block
    const int d    = lane & 15;       // this lane's capsule-dim column
    const int g    = lane >> 4;       // i-subgroup (0..3)

    __shared__ float Gs[8][16][16];   // per-wave Gram scratch (transposed store; G symmetric)

    const float* xb = x + (size_t)b * (II * PP);
    const float* Wj = W + (size_t)j * ((size_t)II * DD * PP);

    // lane's stream: i = t*32 + g*8 + jj, fixed d
    const float* wp = Wj + (size_t)(g * 8) * (DD * PP) + d * PP;
    const float* xp = xb + (size_t)(g * 8) * PP;

    f32x4 acc = {0.f, 0.f, 0.f, 0.f};
    float s0p = 0.f;

    for (int t = 0; t < II / 32; ++t) {
        float v[8];
#pragma unroll
        for (int jj = 0; jj < 8; ++jj) {
            const float4 w0 = *(const float4*)(wp + jj * (DD * PP));
            const float4 w1 = *(const float4*)(wp + jj * (DD * PP) + 4);
            const float4 x0 = *(const float4*)(xp + jj * PP);
            const float4 x1 = *(const float4*)(xp + jj * PP + 4);
            v[jj] = w0.x * x0.x + w0.y * x0.y + w0.z * x0.z + w0.w * x0.w
                  + w1.x * x1.x + w1.y * x1.y + w1.z * x1.z + w1.w * x1.w;
        }
        bf16x8 frag;
#pragma unroll
        for (int jj = 0; jj < 8; ++jj) {
            s0p += v[jj];
            __hip_bfloat16 h = __float2bfloat16(v[jj]);   // RN rounding
            frag[jj] = __builtin_bit_cast(short, h);
        }
        acc = __builtin_amdgcn_mfma_f32_16x16x32_bf16(frag, frag, acc, 0, 0, 0);
        wp += 32 * (DD * PP);
        xp += 32 * PP;
    }

    // s0: lane holds partial for its d over its i-subset; fold the 4 i-groups.
    s0p += __shfl_xor(s0p, 16);
    s0p += __shfl_xor(s0p, 32);   // every lane now has s0[d] for d = lane&15

    // C/D layout: acc[r] = G[g*4+r][d]. Store transposed (G symmetric):
    // Gs[w][d][g*4+r]  -> contiguous 16B per lane.
    *(float4*)&Gs[wave][d][g * 4] = *(float4*)&acc;

    __syncthreads();   // cheap; guarantees LDS visibility for the tail

    // Routing tail: 3 fixed-point steps on 16 scalars, lanes 0..15 of each wave.
    if (lane < DD) {
        float s = s0p;       // lane == d here
        float u = 0.f;
        for (int r = 0; r < 3; ++r) {
            float n = s * s;
            n += __shfl_xor(n, 1);
            n += __shfl_xor(n, 2);
            n += __shfl_xor(n, 4);
            n += __shfl_xor(n, 8);
            u = s / n;       // reference divides by the SQUARED norm
            if (r < 2) {
                float gu = 0.f;
#pragma unroll
                for (int e = 0; e < DD; ++e)
                    gu += Gs[wave][e][lane] * __shfl(u, e);  // Gs[e][d] = G[d][e]
                s += gu;
            }
        }
        out[((size_t)b * JJ + j) * DD + lane] = u;
    }
}

extern "C" void kernel_launch(void* const* d_in, const int* in_sizes, int n_in,
                              void* d_out, int out_size, void* d_ws, size_t ws_size,
                              hipStream_t stream) {
    const float* x = (const float*)d_in[0];   // [64, 4096, 8]
    const float* W = (const float*)d_in[1];   // [64, 4096, 16, 8]
    float* out = (float*)d_out;               // [64, 64, 16]

    dim3 grid((BB / 8) * JJ);   // 512 blocks: 8 b-groups x 64 j
    dim3 block(512);            // 8 waves: one b per wave
    caps_kernel<<<grid, block, 0, stream>>>(x, W, out);
}

// Round 4
// 456.344 us; speedup vs baseline: 2.8650x; 1.4818x over previous
//
#include <hip/hip_runtime.h>
#include <hip/hip_bf16.h>

// CapsuleLayer routing, algebraically collapsed (exact):
//   v[i,d] = sum_p W[j,i,d,p] x[b,i,p];  s0[d] = sum_i v;  G = V^T V (MFMA)
//   u = s/||s||^2 ; s += G u (x2) ; out = u
// Round-4 structure (round-3 was L1-request-bound: 16.8 GB of dwordx4
// requests, 16x duplicated x reads):
//  - 4 b's per wave: W regs amortized 4x (W request traffic /4)
//  - x deduped: block stages x-tile to LDS via global_load_lds with a
//    per-lane-source transposed gather + XOR(g) swizzle; waves read it as
//    broadcast ds_read_b128 (16 d-lanes same addr; 4 g-groups distinct
//    bank-quads -> conflict-free)
//  - 8 waves = 4 b-quads x 2 I-halves; halves reduced in LDS tail
//  - 2-phase pipeline: stage(t+1) issued before compute(t), 1 barrier/chunk

#define II 4096
#define DD 16
#define PP 8
#define JJ 64

typedef __attribute__((ext_vector_type(8))) short bf16x8;
typedef __attribute__((ext_vector_type(4))) float f32x4;
typedef __attribute__((address_space(3))) unsigned int lds_uint;
typedef const __attribute__((address_space(1))) unsigned int glb_uint;

__global__ __launch_bounds__(512, 2) void caps_kernel(
    const float* __restrict__ x,   // [64, 4096, 8]
    const float* __restrict__ W,   // [64, 4096, 16, 8]
    float* __restrict__ out)       // [64, 64, 16]
{
    const int bid = blockIdx.x;          // bid = bg*64 + j -> same-j blocks same XCD
    const int j   = bid & 63;
    const int bg  = bid >> 6;

    const int tid  = threadIdx.x;
    const int wave = tid >> 6;
    const int lane = tid & 63;
    const int q    = wave & 3;           // b-quad (b_loc = q*4 + bb)
    const int h    = wave >> 2;          // I-half
    const int d    = lane & 15;          // capsule dim (MFMA col)
    const int g    = lane >> 4;          // i-subgroup (MFMA k-group)

    // x-tile slot layout: slot enc(i_loc,b_loc,pp) = i_loc*32 + b_loc*2 + pp
    // stored at t = enc ^ (g(i_loc)<<1)  (g = i_loc>>3; XOR hits b-bits only)
    __shared__ float4 xtile[2][2][1024]; // [buf][half][slot]  64 KB
    __shared__ float  Gs[2][16][16][16]; // [half][b_loc][col d][row]  32 KB
    __shared__ float  s0s[2][16][16];    //  2 KB

    const float* Wj   = W + (size_t)j * (II * DD * PP);
    const float* xblk = x + (size_t)(bg * 16) * (II * PP);
    const int ibase   = h * 2048;

    f32x4 acc[4];
    float s0p[4];
#pragma unroll
    for (int bb = 0; bb < 4; ++bb) { acc[bb] = (f32x4){0.f,0.f,0.f,0.f}; s0p[bb] = 0.f; }

    auto stage = [&](int buf, int t) {
#pragma unroll
        for (int u = 0; u < 4; ++u) {
            const int s     = q * 256 + u * 64 + lane;  // slot this lane fills
            const int i_loc = s >> 5;
            const int gg    = (s >> 8) & 3;             // = i_loc>>3
            const int low5  = (s & 31) ^ (gg << 1);     // inverse swizzle
            const int b_loc = low5 >> 1;
            const int pp    = low5 & 1;
            const float* src = xblk + (size_t)b_loc * (II * PP)
                             + (size_t)(ibase + t * 32 + i_loc) * PP + pp * 4;
            __builtin_amdgcn_global_load_lds((glb_uint*)src,
                (lds_uint*)&xtile[buf][h][q * 256 + u * 64], 16, 0, 0);
        }
    };

    stage(0, 0);
    __syncthreads();

    // per-bb swizzled x base slot: bits disjoint (g*256 | jj*32 | swizzled b-bits)
    int xoff[4];
#pragma unroll
    for (int bb = 0; bb < 4; ++bb)
        xoff[bb] = g * 256 + (((q * 4 + bb) * 2) ^ (g << 1));

    for (int t = 0; t < 64; ++t) {
        const int buf = t & 1;
        if (t < 63) stage(buf ^ 1, t + 1);   // issue early; hidden under compute

        const float* wrow = Wj + (size_t)(ibase + t * 32 + g * 8) * (DD * PP) + d * PP;
        const float4* xb  = &xtile[buf][h][0];
        const float4* xbb0 = xb + xoff[0];
        const float4* xbb1 = xb + xoff[1];
        const float4* xbb2 = xb + xoff[2];
        const float4* xbb3 = xb + xoff[3];

        bf16x8 frag[4];
#pragma unroll
        for (int jj = 0; jj < 8; ++jj) {
            const float4 w0 = *(const float4*)(wrow + jj * (DD * PP));
            const float4 w1 = *(const float4*)(wrow + jj * (DD * PP) + 4);
            const float4* xp[4] = { xbb0 + jj * 32, xbb1 + jj * 32,
                                    xbb2 + jj * 32, xbb3 + jj * 32 };
#pragma unroll
            for (int bb = 0; bb < 4; ++bb) {
                const float4 x0 = xp[bb][0];   // broadcast ds_read_b128
                const float4 x1 = xp[bb][1];
                float v = w0.x * x0.x + w0.y * x0.y + w0.z * x0.z + w0.w * x0.w
                        + w1.x * x1.x + w1.y * x1.y + w1.z * x1.z + w1.w * x1.w;
                s0p[bb] += v;
                __hip_bfloat16 hh = __float2bfloat16(v);
                frag[bb][jj] = __builtin_bit_cast(short, hh);
            }
        }
#pragma unroll
        for (int bb = 0; bb < 4; ++bb)
            acc[bb] = __builtin_amdgcn_mfma_f32_16x16x32_bf16(frag[bb], frag[bb], acc[bb], 0, 0, 0);

        __syncthreads();   // stage(t+1) drained + all waves done with buf
    }

    // fold s0 over the 4 g-subgroups
#pragma unroll
    for (int bb = 0; bb < 4; ++bb) {
        s0p[bb] += __shfl_xor(s0p[bb], 16);
        s0p[bb] += __shfl_xor(s0p[bb], 32);
    }

    // park partials: Gs[h][b][d][g*4+r] = G[row=g*4+r][col=d] (C/D layout)
#pragma unroll
    for (int bb = 0; bb < 4; ++bb) {
        *(float4*)&Gs[h][q * 4 + bb][d][g * 4] = *(float4*)&acc[bb];
        if (lane < 16) s0s[h][q * 4 + bb][lane] = s0p[bb];
    }
    __syncthreads();

    // routing tail: 16 threads per b (16 b's -> first 256 threads)
    if (tid < 256) {
        const int b_loc = tid >> 4;
        const int dd    = tid & 15;
        float s = s0s[0][b_loc][dd] + s0s[1][b_loc][dd];
        float u = 0.f;
        for (int r = 0; r < 3; ++r) {
            float n = s * s;
            n += __shfl_xor(n, 1);
            n += __shfl_xor(n, 2);
            n += __shfl_xor(n, 4);
            n += __shfl_xor(n, 8);
            u = s / n;                       // reference: divide by SQUARED norm
            if (r < 2) {
                float gu = 0.f;
#pragma unroll
                for (int e = 0; e < 16; ++e) {
                    const float ge = Gs[0][b_loc][e][dd] + Gs[1][b_loc][e][dd];
                    gu += ge * __shfl(u, (lane & 48) + e);
                }
                s += gu;
            }
        }
        out[((size_t)(bg * 16 + b_loc) * JJ + j) * DD + dd] = u;
    }
}

extern "C" void kernel_launch(void* const* d_in, const int* in_sizes, int n_in,
                              void* d_out, int out_size, void* d_ws, size_t ws_size,
                              hipStream_t stream) {
    const float* x = (const float*)d_in[0];   // [64, 4096, 8]
    const float* W = (const float*)d_in[1];   // [64, 4096, 16, 8]
    float* out = (float*)d_out;               // [64, 64, 16]

    dim3 grid(4 * 64);    // bg(4) x j(64) = 256 blocks (1/CU)
    dim3 block(512);      // 8 waves: 4 b-quads x 2 I-halves
    caps_kernel<<<grid, block, 0, stream>>>(x, W, out);
}